// Round 11
// baseline (558.398 us; speedup 1.0000x reference)
//
#include <hip/hip_runtime.h>
#include <math.h>

// Problem geometry (fixed): B=8, C=4, H=W=256; 24 = B*3 slices per mask type.
#define HWTOT 65536
#define WD 256
#define NSL 24
#define NBLK 512
#define MAGIC 0x13572468u

// Workspace layout (bytes) — flag protocol handles the 0xAA poison.
static constexpr size_t OFF_FLAG = 0;                                    // u32 init flag
static constexpr size_t OFF_CNT8 = 64;                                   // 8 u32 arrive counters (spread)
static constexpr size_t OFF_PART = 256;                                  // NBLK f32 block partials
static constexpr size_t OFF_MASK = 24832;                                // 24*65536 u8 (bit0=P, bit1=T)
static constexpr size_t OFF_ERR  = OFF_MASK + (size_t)NSL * HWTOT;       // f16
static constexpr size_t OFF_BITS = OFF_ERR + (size_t)NSL * HWTOT * 2;    // u32[2][24][8][256]
static constexpr size_t OFF_GC   = OFF_BITS + (size_t)2 * NSL * 8 * WD * 4; // u16[2][24][256][256]

// Per-field vertical distances for 32 rows of one column (validated r7).
__device__ __forceinline__ void vgc_field(
    const unsigned Y[8], bool valid, int kk, int w,
    unsigned short* __restrict__ gout)   // global, [256][WD] slice plane
{
    unsigned wk = 0;
    #pragma unroll
    for (int j = 0; j < 8; ++j) if (j == kk) wk = Y[j];

    int ls = -1000, lc = -1000;
    #pragma unroll
    for (int j = 0; j < 8; ++j) {
        if (j < kk) {
            unsigned z = Y[j], zc = ~Y[j];
            ls = z  ? (32 * j + 31 - __clz(z))  : ls;
            lc = zc ? (32 * j + 31 - __clz(zc)) : lc;
        }
    }
    unsigned dupk[16];
    #pragma unroll
    for (int r = 0; r < 32; ++r) {
        int h = 32 * kk + r;
        int b = (wk >> r) & 1;
        int du = min(h - (b ? lc : ls), 512);
        if (r & 1) dupk[r >> 1] |= (unsigned)du << 16;
        else       dupk[r >> 1]  = (unsigned)du;
        ls = b ? h : ls;
        lc = b ? lc : h;
    }
    int ns = 100000, nc = 100000;
    #pragma unroll
    for (int j = 7; j >= 0; --j) {
        if (j > kk) {
            unsigned z = Y[j], zc = ~Y[j];
            ns = z  ? (32 * j + (__ffs(z)  - 1)) : ns;
            nc = zc ? (32 * j + (__ffs(zc) - 1)) : nc;
        }
    }
    #pragma unroll
    for (int r = 31; r >= 0; --r) {
        int h = 32 * kk + r;
        int b = (wk >> r) & 1;
        int dd = min((b ? nc : ns) - h, 512);
        unsigned pk = dupk[r >> 1];
        int du = (r & 1) ? (int)(pk >> 16) : (int)(pk & 0xffffu);
        int gcv = min(du, dd);
        gcv = valid ? gcv : 0;
        gout[h * WD + w] = (unsigned short)gcv;
        ns = b ? h : ns;
        nc = b ? nc : h;
    }
}

// Software grid barrier: arrive on cnt8[bid&7] (RMW, 64/line), release by
// spin-summing the 8 counters with device-scope coherent LOADS (no RMW spam).
__device__ __forceinline__ void gridbar(unsigned* cnt8, int bid, unsigned target)
{
    __syncthreads();
    if (threadIdx.x == 0) {
        __threadfence();
        __hip_atomic_fetch_add(&cnt8[bid & 7], 1u,
                               __ATOMIC_ACQ_REL, __HIP_MEMORY_SCOPE_AGENT);
        unsigned sum;
        do {
            sum = 0;
            #pragma unroll
            for (int j = 0; j < 8; ++j)
                sum += __hip_atomic_load(&cnt8[j], __ATOMIC_ACQUIRE,
                                         __HIP_MEMORY_SCOPE_AGENT);
        } while (sum < target);
        __threadfence();
    }
    __syncthreads();
}

// ---------------- One persistent kernel, 5 phases ----------------
__global__ __launch_bounds__(256, 4) void k_all(
    const float* __restrict__ pS, const float* __restrict__ pT,
    unsigned char* __restrict__ mask, _Float16* __restrict__ err,
    unsigned* __restrict__ bits, unsigned short* __restrict__ gc,
    float* __restrict__ partials, unsigned* __restrict__ flag,
    unsigned* __restrict__ cnt8, float* __restrict__ out)
{
    const int bid = blockIdx.x;
    const int tid = bid * 256 + threadIdx.x;     // 0 .. 131071

    __shared__ float4   g2[768];
    __shared__ unsigned rb[4][4];
    __shared__ float    wred[4];
    __shared__ double   dred[256];

    // ---- init: block 0 zeroes counters, releases flag; all blocks wait ----
    if (bid == 0 && threadIdx.x == 0) {
        #pragma unroll
        for (int j = 0; j < 8; ++j)
            __hip_atomic_store(&cnt8[j], 0u, __ATOMIC_RELAXED, __HIP_MEMORY_SCOPE_AGENT);
        __hip_atomic_store(flag, MAGIC, __ATOMIC_RELEASE, __HIP_MEMORY_SCOPE_AGENT);
    }
    if (threadIdx.x == 0) {
        while (__hip_atomic_load(flag, __ATOMIC_ACQUIRE, __HIP_MEMORY_SCOPE_AGENT) != MAGIC) {}
    }
    __syncthreads();

    // ---- Phase 1: softmax / argmax -> mask bytes + err (4 px/thread) ----
    #pragma unroll
    for (int it = 0; it < 4; ++it) {
        int t  = tid + it * (NBLK * 256);        // 0 .. 524287
        int b  = t >> 16;
        int hw = t & (HWTOT - 1);

        const float* ps = pS + (size_t)b * 4 * HWTOT + hw;
        float s0 = ps[0], s1 = ps[HWTOT], s2 = ps[2 * HWTOT], s3 = ps[3 * HWTOT];
        float mx = fmaxf(fmaxf(s0, s1), fmaxf(s2, s3));
        float e0 = expf(s0 - mx), e1 = expf(s1 - mx), e2 = expf(s2 - mx), e3 = expf(s3 - mx);
        float inv = 1.0f / (e0 + e1 + e2 + e3);

        const float* pt = pT + (size_t)b * 4 * HWTOT + hw;
        float t0 = pt[0], t1 = pt[HWTOT], t2 = pt[2 * HWTOT], t3 = pt[3 * HWTOT];
        int lab = 0; float bm = t0;
        if (t1 > bm) { bm = t1; lab = 1; }
        if (t2 > bm) { bm = t2; lab = 2; }
        if (t3 > bm) { bm = t3; lab = 3; }

        float pv[3] = { e1 * inv, e2 * inv, e3 * inv };
        #pragma unroll
        for (int cc = 0; cc < 3; ++cc) {
            int sl = b * 3 + cc;
            bool mp = pv[cc] > 0.5f;
            bool mt = (lab == cc + 1);
            mask[(size_t)sl * HWTOT + hw] = (unsigned char)((mp ? 1 : 0) | (mt ? 2 : 0));
            float tcv = mt ? 1.0f : 0.0f;
            float ev = (pv[cc] - tcv) * (pv[cc] - tcv);
            err[(size_t)sl * HWTOT + hw] = (_Float16)ev;
        }
    }
    gridbar(cnt8, bid, NBLK);

    // ---- Phase 2: pack 32-row groups into column bitmaps (blocks 0..191) ----
    if (tid < NSL * 8 * 256) {
        int s = tid >> 11;
        int k = (tid >> 8) & 7;
        int w = tid & 255;
        const unsigned char* m = mask + (size_t)s * HWTOT + k * 32 * WD + w;

        unsigned vp = 0, vt = 0;
        #pragma unroll
        for (int i = 0; i < 32; ++i) {
            unsigned v = m[i * WD];
            vp |= (v & 1u) << i;
            vt |= ((v >> 1) & 1u) << i;
        }
        bits[((size_t)(0 * NSL + s) * 8 + k) * WD + w] = vp;
        bits[((size_t)(1 * NSL + s) * 8 + k) * WD + w] = vt;
    }
    gridbar(cnt8, bid, 2 * NBLK);

    // ---- Phase 3: vertical distances + slice validity (blocks 0..191) ----
    if (tid < NSL * 8 * 256) {
        int s  = tid >> 11;
        int kk = (tid >> 8) & 7;
        int w  = threadIdx.x;

        unsigned YP[8], YT[8];
        #pragma unroll
        for (int j = 0; j < 8; ++j) {
            YP[j] = bits[((size_t)(0 * NSL + s) * 8 + j) * WD + w];
            YT[j] = bits[((size_t)(1 * NSL + s) * 8 + j) * WD + w];
        }

        unsigned oP = 0, aP = 0xFFFFFFFFu, oT = 0, aT = 0xFFFFFFFFu;
        #pragma unroll
        for (int j = 0; j < 8; ++j) {
            oP |= YP[j]; aP &= YP[j];
            oT |= YT[j]; aT &= YT[j];
        }
        #pragma unroll
        for (int i = 1; i < 64; i <<= 1) {
            oP |= __shfl_xor(oP, i); aP &= __shfl_xor(aP, i);
            oT |= __shfl_xor(oT, i); aT &= __shfl_xor(aT, i);
        }
        if ((w & 63) == 0) {
            int wv = w >> 6;
            rb[wv][0] = oP; rb[wv][1] = aP; rb[wv][2] = oT; rb[wv][3] = aT;
        }
        __syncthreads();
        oP = rb[0][0] | rb[1][0] | rb[2][0] | rb[3][0];
        aP = rb[0][1] & rb[1][1] & rb[2][1] & rb[3][1];
        oT = rb[0][2] | rb[1][2] | rb[2][2] | rb[3][2];
        aT = rb[0][3] & rb[1][3] & rb[2][3] & rb[3][3];
        bool validP = (oP != 0u) && (aP != 0xFFFFFFFFu);
        bool validT = (oT != 0u) && (aT != 0xFFFFFFFFu);

        vgc_field(YP, validP, kk, w, gc + (size_t)(0 * NSL + s) * HWTOT);
        vgc_field(YT, validT, kk, w, gc + (size_t)(1 * NSL + s) * HWTOT);
    }
    gridbar(cnt8, bid, 3 * NBLK);

    // ---- Phase 4: horizontal radius-limited min + loss, 12 rows/block ----
    float accum = 0.0f;
    {
        float4 inf4 = make_float4(1e30f, 1e30f, 1e30f, 1e30f);
        int jo = threadIdx.x;
        g2[jo] = inf4;
        g2[512 + jo] = inf4;
        __syncthreads();

        #pragma unroll 1
        for (int it = 0; it < 12; ++it) {
            int item = bid + it * NBLK;          // 0 .. 6143, round-robin slices
            int s  = item >> 8;
            int h  = item & 255;

            size_t rbase = (size_t)s * HWTOT + h * WD + jo;
            int gcP = gc[rbase];
            int gcT = gc[(size_t)NSL * HWTOT + rbase];
            unsigned wP = bits[((size_t)(0 * NSL + s) * 8 + (h >> 5)) * WD + jo];
            unsigned wT = bits[((size_t)(1 * NSL + s) * 8 + (h >> 5)) * WD + jo];
            bool selP = (wP >> (h & 31)) & 1;
            bool selT = (wT >> (h & 31)) & 1;

            float fP = (float)(gcP * gcP);
            float fT = (float)(gcT * gcT);
            g2[256 + jo] = make_float4(selP ? fP : 0.0f, selP ? 0.0f : fP,
                                       selT ? fT : 0.0f, selT ? 0.0f : fT);

            int R = min(max(gcP, gcT), 256);
            #pragma unroll
            for (int i = 1; i < 64; i <<= 1) R = max(R, __shfl_xor(R, i));

            float m1 = fP;
            float m2 = fT;
            __syncthreads();

            for (int dd = 1; dd < R; ++dd) {
                float4 L  = g2[256 + jo - dd];
                float4 Rv = g2[256 + jo + dd];
                float d2 = (float)(dd * dd);
                float c1 = fminf(selP ? L.x : L.y, selP ? Rv.x : Rv.y);
                float c2 = fminf(selT ? L.z : L.w, selT ? Rv.z : Rv.w);
                m1 = fminf(m1, c1 + d2);
                m2 = fminf(m2, c2 + d2);
            }

            accum += (float)err[rbase] * (m1 + m2);
            __syncthreads();                     // before next row overwrites g2
        }
    }
    // block reduce -> partials[bid] (plain store; visible via barrier fence)
    #pragma unroll
    for (int off = 32; off > 0; off >>= 1) accum += __shfl_down(accum, off);
    if ((threadIdx.x & 63) == 0) wred[threadIdx.x >> 6] = accum;
    __syncthreads();
    if (threadIdx.x == 0)
        partials[bid] = wred[0] + wred[1] + wred[2] + wred[3];
    gridbar(cnt8, bid, 4 * NBLK);

    // ---- Phase 5: block 0 final reduce (double) + log ----
    if (bid == 0) {
        int t = threadIdx.x;
        double acc = (double)partials[t] + (double)partials[t + 256];
        dred[t] = acc;
        __syncthreads();
        for (int off = 128; off > 0; off >>= 1) {
            if (t < off) dred[t] += dred[t + off];
            __syncthreads();
        }
        if (t == 0) {
            double loss = dred[0] / (double)((size_t)NSL * HWTOT);
            out[0] = (float)log(loss + 1.0);
        }
    }
}

extern "C" void kernel_launch(void* const* d_in, const int* in_sizes, int n_in,
                              void* d_out, int out_size, void* d_ws, size_t ws_size,
                              hipStream_t stream)
{
    const float* pS = (const float*)d_in[0];
    const float* pT = (const float*)d_in[1];
    float* out = (float*)d_out;

    char* ws = (char*)d_ws;
    unsigned*       flag  = (unsigned*)(ws + OFF_FLAG);
    unsigned*       cnt8  = (unsigned*)(ws + OFF_CNT8);
    float*          parts = (float*)(ws + OFF_PART);
    unsigned char*  mask  = (unsigned char*)(ws + OFF_MASK);
    _Float16*       err   = (_Float16*)(ws + OFF_ERR);
    unsigned*       bits  = (unsigned*)(ws + OFF_BITS);
    unsigned short* gcp   = (unsigned short*)(ws + OFF_GC);

    k_all<<<dim3(NBLK), dim3(256), 0, stream>>>(
        pS, pT, mask, err, bits, gcp, parts, flag, cnt8, out);
}

// Round 12
// 105.880 us; speedup vs baseline: 5.2739x; 5.2739x over previous
//
#include <hip/hip_runtime.h>
#include <math.h>

// Problem geometry (fixed): B=8, C=4, H=W=256; 24 = B*3 slices per mask type.
#define HWTOT 65536
#define WD 256
#define NSL 24

// Workspace layout (bytes) — everything written before read; no memset needed.
static constexpr size_t OFF_PART = 256;                                  // 6144 f32
static constexpr size_t OFF_MASK = 24832;                                // 24*65536 u8 (bit0=P, bit1=T)
static constexpr size_t OFF_ERR  = OFF_MASK + (size_t)NSL * HWTOT;       // f16
static constexpr size_t OFF_BITS = OFF_ERR + (size_t)NSL * HWTOT * 2;    // u32[2][24][8][256]
static constexpr size_t OFF_GC   = OFF_BITS + (size_t)2 * NSL * 8 * WD * 4; // u16[2][24][256][256]
// bits: bit r of bits[f][s][k][w] = mask bit f at (row 32k+r, col w).
// gc[f][s][h][w] = vertical L1 distance to nearest differing pixel in column
// (clamp 512), pre-zeroed when the slice is invalid (empty or full mask).

// ---------------- Kernel 1: masks + err (validated r4-r7, absmax=0) ----------
__global__ __launch_bounds__(256) void k_mask(
    const float* __restrict__ pS, const float* __restrict__ pT,
    unsigned char* __restrict__ mask, _Float16* __restrict__ err)
{
    int blk = blockIdx.x;
    int b   = blk >> 8;          // image 0..7
    int hw  = (blk & 255) * 256 + threadIdx.x;

    const float* ps = pS + (size_t)b * 4 * HWTOT + hw;
    float s0 = ps[0], s1 = ps[HWTOT], s2 = ps[2 * HWTOT], s3 = ps[3 * HWTOT];
    float mx = fmaxf(fmaxf(s0, s1), fmaxf(s2, s3));
    float e0 = expf(s0 - mx), e1 = expf(s1 - mx), e2 = expf(s2 - mx), e3 = expf(s3 - mx);
    float inv = 1.0f / (e0 + e1 + e2 + e3);

    const float* pt = pT + (size_t)b * 4 * HWTOT + hw;
    float t0 = pt[0], t1 = pt[HWTOT], t2 = pt[2 * HWTOT], t3 = pt[3 * HWTOT];
    int lab = 0; float bm = t0;
    if (t1 > bm) { bm = t1; lab = 1; }
    if (t2 > bm) { bm = t2; lab = 2; }
    if (t3 > bm) { bm = t3; lab = 3; }

    float pv[3] = { e1 * inv, e2 * inv, e3 * inv };
    #pragma unroll
    for (int cc = 0; cc < 3; ++cc) {
        int sl = b * 3 + cc;
        bool mp = pv[cc] > 0.5f;
        bool mt = (lab == cc + 1);
        mask[(size_t)sl * HWTOT + hw] = (unsigned char)((mp ? 1 : 0) | (mt ? 2 : 0));
        float tcv = mt ? 1.0f : 0.0f;
        float ev = (pv[cc] - tcv) * (pv[cc] - tcv);
        err[(size_t)sl * HWTOT + hw] = (_Float16)ev;
    }
}

// Per-field vertical distances for 32 rows of one column (validated r7).
__device__ __forceinline__ void vgc_field(
    const unsigned Y[8], bool valid, int kk, int w,
    unsigned short* __restrict__ gout)   // global, [256][WD] slice plane
{
    unsigned wk = 0;
    #pragma unroll
    for (int j = 0; j < 8; ++j) if (j == kk) wk = Y[j];

    int ls = -1000, lc = -1000;
    #pragma unroll
    for (int j = 0; j < 8; ++j) {
        if (j < kk) {
            unsigned z = Y[j], zc = ~Y[j];
            ls = z  ? (32 * j + 31 - __clz(z))  : ls;
            lc = zc ? (32 * j + 31 - __clz(zc)) : lc;
        }
    }
    unsigned dupk[16];
    #pragma unroll
    for (int r = 0; r < 32; ++r) {
        int h = 32 * kk + r;
        int b = (wk >> r) & 1;
        int du = min(h - (b ? lc : ls), 512);
        if (r & 1) dupk[r >> 1] |= (unsigned)du << 16;
        else       dupk[r >> 1]  = (unsigned)du;
        ls = b ? h : ls;
        lc = b ? lc : h;
    }
    int ns = 100000, nc = 100000;
    #pragma unroll
    for (int j = 7; j >= 0; --j) {
        if (j > kk) {
            unsigned z = Y[j], zc = ~Y[j];
            ns = z  ? (32 * j + (__ffs(z)  - 1)) : ns;
            nc = zc ? (32 * j + (__ffs(zc) - 1)) : nc;
        }
    }
    #pragma unroll
    for (int r = 31; r >= 0; --r) {
        int h = 32 * kk + r;
        int b = (wk >> r) & 1;
        int dd = min((b ? nc : ns) - h, 512);
        unsigned pk = dupk[r >> 1];
        int du = (r & 1) ? (int)(pk >> 16) : (int)(pk & 0xffffu);
        int gcv = min(du, dd);
        gcv = valid ? gcv : 0;
        gout[h * WD + w] = (unsigned short)gcv;
        ns = b ? h : ns;
        nc = b ? nc : h;
    }
}

// ---------------- Kernel 2: pack (from mask bytes) + vgc, fused -------------
// Block = (slice s, rowgroup kk). Thread = column. Builds the FULL column
// bitmap from mask bytes (L2-hot, 8x reuse), stores only its own kk's two
// words for k_row, computes validity + vertical distances for its 32 rows.
__global__ __launch_bounds__(256) void k_packvgc(
    const unsigned char* __restrict__ mask, unsigned* __restrict__ bits,
    unsigned short* __restrict__ gc)
{
    int s  = blockIdx.x;
    int kk = blockIdx.y;
    int w  = threadIdx.x;
    const unsigned char* m = mask + (size_t)s * HWTOT + w;

    unsigned YP[8], YT[8];
    #pragma unroll
    for (int k = 0; k < 8; ++k) {
        unsigned vp = 0, vt = 0;
        #pragma unroll
        for (int i = 0; i < 32; ++i) {
            unsigned v = m[(k * 32 + i) * WD];
            vp |= (v & 1u) << i;
            vt |= ((v >> 1) & 1u) << i;
        }
        YP[k] = vp; YT[k] = vt;
    }
    // store only own rowgroup's words (siblings store the rest)
    bits[((size_t)(0 * NSL + s) * 8 + kk) * WD + w] = YP[kk];
    bits[((size_t)(1 * NSL + s) * 8 + kk) * WD + w] = YT[kk];

    // slice validity (any && !all) via block OR/AND reduce (r7 verbatim)
    unsigned oP = 0, aP = 0xFFFFFFFFu, oT = 0, aT = 0xFFFFFFFFu;
    #pragma unroll
    for (int j = 0; j < 8; ++j) {
        oP |= YP[j]; aP &= YP[j];
        oT |= YT[j]; aT &= YT[j];
    }
    #pragma unroll
    for (int i = 1; i < 64; i <<= 1) {
        oP |= __shfl_xor(oP, i); aP &= __shfl_xor(aP, i);
        oT |= __shfl_xor(oT, i); aT &= __shfl_xor(aT, i);
    }
    __shared__ unsigned rb[4][4];
    if ((w & 63) == 0) {
        int wv = w >> 6;
        rb[wv][0] = oP; rb[wv][1] = aP; rb[wv][2] = oT; rb[wv][3] = aT;
    }
    __syncthreads();
    oP = rb[0][0] | rb[1][0] | rb[2][0] | rb[3][0];
    aP = rb[0][1] & rb[1][1] & rb[2][1] & rb[3][1];
    oT = rb[0][2] | rb[1][2] | rb[2][2] | rb[3][2];
    aT = rb[0][3] & rb[1][3] & rb[2][3] & rb[3][3];
    bool validP = (oP != 0u) && (aP != 0xFFFFFFFFu);
    bool validT = (oT != 0u) && (aT != 0xFFFFFFFFu);

    vgc_field(YP, validP, kk, w, gc + (size_t)(0 * NSL + s) * HWTOT);
    vgc_field(YT, validT, kk, w, gc + (size_t)(1 * NSL + s) * HWTOT);
}

// ---------------- Kernel 3: horizontal min, radius-limited, fused loss ------
__global__ __launch_bounds__(256) void k_row(
    const _Float16* __restrict__ err, const unsigned* __restrict__ bits,
    const unsigned short* __restrict__ gcArr, float* __restrict__ partials)
{
    int h  = blockIdx.x;        // row 0..255
    int s  = blockIdx.y;        // slice 0..23
    int jo = threadIdx.x;

    __shared__ float4 g2[768];
    __shared__ float  wred[4];

    size_t rbase = (size_t)s * HWTOT + h * WD + jo;
    int gcP = gcArr[rbase];
    int gcT = gcArr[(size_t)NSL * HWTOT + rbase];
    unsigned wP = bits[((size_t)(0 * NSL + s) * 8 + (h >> 5)) * WD + jo];
    unsigned wT = bits[((size_t)(1 * NSL + s) * 8 + (h >> 5)) * WD + jo];
    bool selP = (wP >> (h & 31)) & 1;
    bool selT = (wT >> (h & 31)) & 1;

    float fP = (float)(gcP * gcP);
    float fT = (float)(gcT * gcT);
    g2[256 + jo] = make_float4(selP ? fP : 0.0f, selP ? 0.0f : fP,
                               selT ? fT : 0.0f, selT ? 0.0f : fT);
    float4 inf4 = make_float4(1e30f, 1e30f, 1e30f, 1e30f);
    g2[jo] = inf4;
    g2[512 + jo] = inf4;

    int R = min(max(gcP, gcT), 256);
    #pragma unroll
    for (int i = 1; i < 64; i <<= 1) R = max(R, __shfl_xor(R, i));

    float m1 = fP;
    float m2 = fT;
    __syncthreads();

    for (int dd = 1; dd < R; ++dd) {
        float4 L  = g2[256 + jo - dd];
        float4 Rv = g2[256 + jo + dd];
        float d2 = (float)(dd * dd);
        float c1 = fminf(selP ? L.x : L.y, selP ? Rv.x : Rv.y);
        float c2 = fminf(selT ? L.z : L.w, selT ? Rv.z : Rv.w);
        m1 = fminf(m1, c1 + d2);
        m2 = fminf(m2, c2 + d2);
    }

    float contrib = (float)err[rbase] * (m1 + m2);

    #pragma unroll
    for (int off = 32; off > 0; off >>= 1) contrib += __shfl_down(contrib, off);
    if ((jo & 63) == 0) wred[jo >> 6] = contrib;
    __syncthreads();
    if (jo == 0) partials[s * 256 + h] = wred[0] + wred[1] + wred[2] + wred[3];
}

// ---------------- Kernel 4: final reduce (double) + log ----------------
__global__ __launch_bounds__(256) void k_final(
    const float* __restrict__ partials, float* __restrict__ out)
{
    __shared__ double red[256];
    int t = threadIdx.x;
    double acc = 0.0;
    for (int i = t; i < NSL * 256; i += 256) acc += (double)partials[i];
    red[t] = acc;
    __syncthreads();
    for (int off = 128; off > 0; off >>= 1) {
        if (t < off) red[t] += red[t + off];
        __syncthreads();
    }
    if (t == 0) {
        double loss = red[0] / (double)((size_t)NSL * HWTOT);
        out[0] = (float)log(loss + 1.0);
    }
}

extern "C" void kernel_launch(void* const* d_in, const int* in_sizes, int n_in,
                              void* d_out, int out_size, void* d_ws, size_t ws_size,
                              hipStream_t stream)
{
    const float* pS = (const float*)d_in[0];
    const float* pT = (const float*)d_in[1];
    float* out = (float*)d_out;

    char* ws = (char*)d_ws;
    float*          parts = (float*)(ws + OFF_PART);
    unsigned char*  mask  = (unsigned char*)(ws + OFF_MASK);
    _Float16*       err   = (_Float16*)(ws + OFF_ERR);
    unsigned*       bits  = (unsigned*)(ws + OFF_BITS);
    unsigned short* gcp   = (unsigned short*)(ws + OFF_GC);

    k_mask   <<<dim3(2048),     dim3(256), 0, stream>>>(pS, pT, mask, err);
    k_packvgc<<<dim3(NSL, 8),   dim3(256), 0, stream>>>(mask, bits, gcp);
    k_row    <<<dim3(256, NSL), dim3(256), 0, stream>>>(err, bits, gcp, parts);
    k_final  <<<dim3(1),        dim3(256), 0, stream>>>(parts, out);
}